// Round 1
// baseline (884.777 us; speedup 1.0000x reference)
//
#include <hip/hip_runtime.h>
#include <math.h>

#define BB 16
#define CIN 64
#define HH 64
#define WW 64
#define COUT 128
#define K9 9
#define HW 4096          // HH*WW
#define CK 576           // CIN*K9
#define CKP 577          // padded LDS stride

// ---- workspace layout (floats) ----
#define OFF_OFF   0                         // B*18*HW  = 1179648
#define MASK_OFF  1179648                   // B*9*HW   = 589824
#define Y_OFF     1769472                   // B*COUT*HW= 8388608
#define WT_OFF    10158080                  // CK*COUT  = 73728
#define SAB_OFF   10231808                  // 256
// total 10232064 floats = ~40.9 MB

// ---------------------------------------------------------------------------
// Kernel 0: transpose w_d [co][ck] -> wt [ck][co]
__global__ __launch_bounds__(256) void k_transpose_w(const float* __restrict__ wd,
                                                     float* __restrict__ wt) {
    int i = blockIdx.x * 256 + threadIdx.x;
    if (i >= CK * COUT) return;
    int co = i % COUT;
    int ck = i / COUT;
    wt[i] = wd[co * CK + ck];
}

// ---------------------------------------------------------------------------
// Kernel 1: 3x3 conv producing offset (18 ch) and sigmoid(mask) (9 ch)
__global__ __launch_bounds__(256) void k_conv_pm(const float* __restrict__ x,
                                                 const float* __restrict__ wp,
                                                 const float* __restrict__ bp,
                                                 const float* __restrict__ wm,
                                                 const float* __restrict__ bm,
                                                 float* __restrict__ off,
                                                 float* __restrict__ mask) {
    int pos = blockIdx.x * 256 + threadIdx.x;   // 65536 positions
    int b  = pos >> 12;
    int ho = (pos >> 6) & 63;
    int wo = pos & 63;

    float acc[27];
#pragma unroll
    for (int t = 0; t < 27; ++t) acc[t] = 0.f;

    const float* xb = x + (size_t)b * CIN * HW;
    for (int c = 0; c < CIN; ++c) {
        float xv[9];
#pragma unroll
        for (int kh = 0; kh < 3; ++kh) {
            int iy = ho + kh - 1;
#pragma unroll
            for (int kw = 0; kw < 3; ++kw) {
                int ix = wo + kw - 1;
                bool v = (iy >= 0) && (iy < HH) && (ix >= 0) && (ix < WW);
                xv[kh * 3 + kw] = v ? xb[c * HW + iy * WW + ix] : 0.f;
            }
        }
        // 18 offset channels (weights uniform across block -> scalar loads)
#pragma unroll
        for (int t = 0; t < 18; ++t) {
#pragma unroll
            for (int k = 0; k < 9; ++k)
                acc[t] += xv[k] * wp[t * CK + c * 9 + k];
        }
        // 9 mask channels
#pragma unroll
        for (int t = 0; t < 9; ++t) {
#pragma unroll
            for (int k = 0; k < 9; ++k)
                acc[18 + t] += xv[k] * wm[t * CK + c * 9 + k];
        }
    }
#pragma unroll
    for (int t = 0; t < 18; ++t)
        off[((size_t)b * 18 + t) * HW + ho * WW + wo] = acc[t] + bp[t];
#pragma unroll
    for (int t = 0; t < 9; ++t) {
        float s = acc[18 + t] + bm[t];
        mask[((size_t)b * 9 + t) * HW + ho * WW + wo] = 1.f / (1.f + expf(-s));
    }
}

// ---------------------------------------------------------------------------
// Kernel 2: deformable conv. One block = 16 output positions (same row).
#define PPB 16
__global__ __launch_bounds__(256) void k_deform(const float* __restrict__ x,
                                                const float* __restrict__ off,
                                                const float* __restrict__ mask,
                                                const float* __restrict__ wt,
                                                const float* __restrict__ bd,
                                                float* __restrict__ y) {
    __shared__ float val[PPB * CKP];       // 16*577*4 = 36.9 KB
    __shared__ int   s_y0[PPB * 9];
    __shared__ int   s_x0[PPB * 9];
    __shared__ float s_w[PPB * 9 * 4];     // 4 corner weights (mask folded in)

    const int tile = blockIdx.x;           // 0..4095
    const int pos0 = tile * PPB;
    const int b   = pos0 >> 12;
    const int ho  = (pos0 >> 6) & 63;
    const int wo0 = pos0 & 63;             // multiple of 16
    const int tid = threadIdx.x;

    // phase 1: sampling parameters (16 pos x 9 taps)
    if (tid < PPB * 9) {
        int p = tid / 9, k = tid % 9;
        int wo = wo0 + p;
        float dy = off[(((size_t)b * 18 + 2 * k    ) * HH + ho) * WW + wo];
        float dx = off[(((size_t)b * 18 + 2 * k + 1) * HH + ho) * WW + wo];
        float m  = mask[(((size_t)b * 9 + k) * HH + ho) * WW + wo];
        float py = (float)(ho - 1 + k / 3) + dy;
        float px = (float)(wo - 1 + k % 3) + dx;
        float fy = floorf(py), fx = floorf(px);
        float ly = py - fy, lx = px - fx;
        s_y0[tid] = (int)fy;
        s_x0[tid] = (int)fx;
        s_w[tid * 4 + 0] = (1.f - ly) * (1.f - lx) * m;
        s_w[tid * 4 + 1] = (1.f - ly) * lx * m;
        s_w[tid * 4 + 2] = ly * (1.f - lx) * m;
        s_w[tid * 4 + 3] = ly * lx * m;
    }
    __syncthreads();

    // phase 2: bilinear gather -> val[p][ck], ck = c*9+k
    const float* xb = x + (size_t)b * CIN * HW;
    for (int idx = tid; idx < PPB * CK; idx += 256) {
        int p  = idx / CK;
        int ck = idx - p * CK;
        int c  = ck / 9;
        int k  = ck - c * 9;
        int sk = p * 9 + k;
        int y0 = s_y0[sk], x0 = s_x0[sk];
        const float* xc = xb + c * HW;
        float v = 0.f;
        bool yok0 = (y0 >= 0) & (y0 < HH);
        bool yok1 = (y0 + 1 >= 0) & (y0 + 1 < HH);
        bool xok0 = (x0 >= 0) & (x0 < WW);
        bool xok1 = (x0 + 1 >= 0) & (x0 + 1 < WW);
        if (yok0 && xok0) v += s_w[sk * 4 + 0] * xc[y0 * WW + x0];
        if (yok0 && xok1) v += s_w[sk * 4 + 1] * xc[y0 * WW + x0 + 1];
        if (yok1 && xok0) v += s_w[sk * 4 + 2] * xc[(y0 + 1) * WW + x0];
        if (yok1 && xok1) v += s_w[sk * 4 + 3] * xc[(y0 + 1) * WW + x0 + 1];
        val[p * CKP + ck] = v;
    }
    __syncthreads();

    // phase 3: GEMM  out[p][co] = sum_ck val[p][ck] * wt[ck][co]
    // thread -> position p = tid&15, channel block j = tid>>4 (8 co's)
    const int p = tid & 15;
    const int j = tid >> 4;
    const int co_base = j * 8;
    float acc[8];
#pragma unroll
    for (int i = 0; i < 8; ++i) acc[i] = 0.f;

    const float* vrow = &val[p * CKP];
    for (int ck = 0; ck < CK; ++ck) {
        float v = vrow[ck];
        const float4 w0 = *(const float4*)&wt[ck * COUT + co_base];
        const float4 w1 = *(const float4*)&wt[ck * COUT + co_base + 4];
        acc[0] += v * w0.x; acc[1] += v * w0.y;
        acc[2] += v * w0.z; acc[3] += v * w0.w;
        acc[4] += v * w1.x; acc[5] += v * w1.y;
        acc[6] += v * w1.z; acc[7] += v * w1.w;
    }

    float* yo = y + ((size_t)b * COUT + co_base) * HW + ho * WW + wo0 + p;
#pragma unroll
    for (int i = 0; i < 8; ++i)
        yo[(size_t)i * HW] = acc[i] + bd[co_base + i];
}

// ---------------------------------------------------------------------------
// Kernel 3: per-channel BN stats -> scale/shift
__global__ __launch_bounds__(256) void k_stats(const float* __restrict__ y,
                                               const float* __restrict__ gamma,
                                               const float* __restrict__ beta,
                                               float* __restrict__ sAB) {
    const int c = blockIdx.x;
    float s = 0.f, q = 0.f;
    // B*HW/4 = 16384 float4 per channel
    for (int i4 = threadIdx.x; i4 < BB * HW / 4; i4 += 256) {
        int b = i4 >> 10;
        int pix4 = i4 & 1023;
        float4 v = ((const float4*)&y[((size_t)b * COUT + c) * HW])[pix4];
        s += v.x + v.y + v.z + v.w;
        q += v.x * v.x + v.y * v.y + v.z * v.z + v.w * v.w;
    }
#pragma unroll
    for (int o = 32; o > 0; o >>= 1) {
        s += __shfl_down(s, o);
        q += __shfl_down(q, o);
    }
    __shared__ float ss[4], sq[4];
    int wid = threadIdx.x >> 6;
    if ((threadIdx.x & 63) == 0) { ss[wid] = s; sq[wid] = q; }
    __syncthreads();
    if (threadIdx.x == 0) {
        s = ss[0] + ss[1] + ss[2] + ss[3];
        q = sq[0] + sq[1] + sq[2] + sq[3];
        const float invN = 1.f / (float)(BB * HW);
        float mean = s * invN;
        float var  = q * invN - mean * mean;
        float rinv = rsqrtf(var + 1e-5f);
        float A = gamma[c] * rinv;
        sAB[c]       = A;
        sAB[128 + c] = beta[c] - mean * A;
    }
}

// ---------------------------------------------------------------------------
// Kernel 4: normalize + exact GELU, vectorized
__global__ __launch_bounds__(256) void k_norm_gelu(const float* __restrict__ y,
                                                   const float* __restrict__ sAB,
                                                   float* __restrict__ out) {
    int i4 = blockIdx.x * 256 + threadIdx.x;   // 2097152 float4 total
    if (i4 >= (BB * COUT * HW) / 4) return;
    int c = (i4 >> 10) & 127;
    float A  = sAB[c];
    float Bc = sAB[128 + c];
    float4 v = ((const float4*)y)[i4];
    float4 r;
    float t;
    t = v.x * A + Bc; r.x = 0.5f * t * (1.f + erff(t * 0.70710678118654752f));
    t = v.y * A + Bc; r.y = 0.5f * t * (1.f + erff(t * 0.70710678118654752f));
    t = v.z * A + Bc; r.z = 0.5f * t * (1.f + erff(t * 0.70710678118654752f));
    t = v.w * A + Bc; r.w = 0.5f * t * (1.f + erff(t * 0.70710678118654752f));
    ((float4*)out)[i4] = r;
}

// ---------------------------------------------------------------------------
extern "C" void kernel_launch(void* const* d_in, const int* in_sizes, int n_in,
                              void* d_out, int out_size, void* d_ws, size_t ws_size,
                              hipStream_t stream) {
    const float* x     = (const float*)d_in[0];
    const float* w_p   = (const float*)d_in[1];
    const float* b_p   = (const float*)d_in[2];
    const float* w_m   = (const float*)d_in[3];
    const float* b_m   = (const float*)d_in[4];
    const float* w_d   = (const float*)d_in[5];
    const float* b_d   = (const float*)d_in[6];
    const float* gamma = (const float*)d_in[7];
    const float* beta  = (const float*)d_in[8];
    float* out = (float*)d_out;
    float* ws  = (float*)d_ws;

    float* off  = ws + OFF_OFF;
    float* mask = ws + MASK_OFF;
    float* y    = ws + Y_OFF;
    float* wt   = ws + WT_OFF;
    float* sAB  = ws + SAB_OFF;

    k_transpose_w<<<dim3((CK * COUT + 255) / 256), dim3(256), 0, stream>>>(w_d, wt);
    k_conv_pm<<<dim3(BB * HW / 256), dim3(256), 0, stream>>>(x, w_p, b_p, w_m, b_m, off, mask);
    k_deform<<<dim3(BB * HW / PPB), dim3(256), 0, stream>>>(x, off, mask, wt, b_d, y);
    k_stats<<<dim3(COUT), dim3(256), 0, stream>>>(y, gamma, beta, sAB);
    k_norm_gelu<<<dim3((BB * COUT * HW / 4 + 255) / 256), dim3(256), 0, stream>>>(y, sAB, out);
}

// Round 2
// 449.772 us; speedup vs baseline: 1.9672x; 1.9672x over previous
//
#include <hip/hip_runtime.h>
#include <math.h>

#define BB 16
#define CIN 64
#define HH 64
#define WW 64
#define COUT 128
#define HW 4096          // HH*WW
#define CK 576           // CIN*9
#define CKP 584          // padded LDS stride for val (shorts), 16B-aligned rows

typedef __attribute__((ext_vector_type(8))) short short8;   // 8 bf16 = 4 VGPRs
typedef __attribute__((ext_vector_type(4))) float f32x4;

// ---- workspace layout (float indices) ----
#define OFF_OFF   0                         // B*18*HW  = 1179648
#define MASK_OFF  1179648                   // B*9*HW   = 589824
#define Y_OFF     1769472                   // B*COUT*HW= 8388608
#define WT_OFF    10158080                  // bf16 wtb: CK*COUT shorts = 36864 floats
#define SAB_OFF   10231808                  // 256

__device__ __forceinline__ short f2bf(float f) {
    union { float f; unsigned u; } cv; cv.f = f;
    unsigned u = cv.u;
    unsigned r = (u + 0x7fffu + ((u >> 16) & 1u)) >> 16;
    return (short)r;
}

// ---------------------------------------------------------------------------
// Kernel 0: convert w_d [co][ck] f32 -> bf16, same layout (no transpose needed:
// B-operand wants [co][k] rows since we stage it N-major in LDS).
__global__ __launch_bounds__(256) void k_wd2bf(const float* __restrict__ wd,
                                               short* __restrict__ wtb) {
    int i = blockIdx.x * 256 + threadIdx.x;
    if (i < CK * COUT) wtb[i] = f2bf(wd[i]);
}

// ---------------------------------------------------------------------------
// Kernel 1: 3x3 conv producing offset (18 ch) and sigmoid(mask) (9 ch)  [unchanged]
__global__ __launch_bounds__(256) void k_conv_pm(const float* __restrict__ x,
                                                 const float* __restrict__ wp,
                                                 const float* __restrict__ bp,
                                                 const float* __restrict__ wm,
                                                 const float* __restrict__ bm,
                                                 float* __restrict__ off,
                                                 float* __restrict__ mask) {
    int pos = blockIdx.x * 256 + threadIdx.x;   // 65536 positions
    int b  = pos >> 12;
    int ho = (pos >> 6) & 63;
    int wo = pos & 63;

    float acc[27];
#pragma unroll
    for (int t = 0; t < 27; ++t) acc[t] = 0.f;

    const float* xb = x + (size_t)b * CIN * HW;
    for (int c = 0; c < CIN; ++c) {
        float xv[9];
#pragma unroll
        for (int kh = 0; kh < 3; ++kh) {
            int iy = ho + kh - 1;
#pragma unroll
            for (int kw = 0; kw < 3; ++kw) {
                int ix = wo + kw - 1;
                bool v = (iy >= 0) && (iy < HH) && (ix >= 0) && (ix < WW);
                xv[kh * 3 + kw] = v ? xb[c * HW + iy * WW + ix] : 0.f;
            }
        }
#pragma unroll
        for (int t = 0; t < 18; ++t) {
#pragma unroll
            for (int k = 0; k < 9; ++k)
                acc[t] += xv[k] * wp[t * CK + c * 9 + k];
        }
#pragma unroll
        for (int t = 0; t < 9; ++t) {
#pragma unroll
            for (int k = 0; k < 9; ++k)
                acc[18 + t] += xv[k] * wm[t * CK + c * 9 + k];
        }
    }
#pragma unroll
    for (int t = 0; t < 18; ++t)
        off[((size_t)b * 18 + t) * HW + ho * WW + wo] = acc[t] + bp[t];
#pragma unroll
    for (int t = 0; t < 9; ++t) {
        float s = acc[18 + t] + bm[t];
        mask[((size_t)b * 9 + t) * HW + ho * WW + wo] = 1.f / (1.f + expf(-s));
    }
}

// ---------------------------------------------------------------------------
// Kernel 2: deformable conv as implicit bf16 MFMA GEMM.
// Block = 32 output positions (half an image row), 256 threads = 4 waves.
// Tile: M=32 (positions) x N=128 (all out channels), K=576 in 18 chunks of 32.
#define MPB 32
__global__ __launch_bounds__(256) void k_deform(const float* __restrict__ x,
                                                const float* __restrict__ off,
                                                const float* __restrict__ mask,
                                                const short* __restrict__ wtb,
                                                const float* __restrict__ bd,
                                                float* __restrict__ y) {
    __shared__ short val[MPB * CKP];       // 37376 B, bf16 A-tile [p][ck]
    __shared__ short wt[COUT * 40];        // 10240 B, bf16 B-tile [co][k_local] pad 32->40
    __shared__ int   s_yx[MPB * 9];        // packed (y0 low16, x0 high16)
    __shared__ float s_w[MPB * 9 * 4];     // 4 corner weights (mask folded in)
    // total 53376 B -> 3 blocks/CU

    const int pos0 = blockIdx.x * MPB;
    const int b   = pos0 >> 12;
    const int ho  = (pos0 >> 6) & 63;
    const int wo0 = pos0 & 63;             // 0 or 32
    const int tid = threadIdx.x;

    // phase 1: sampling parameters (32 pos x 9 taps)
    for (int t = tid; t < MPB * 9; t += 256) {
        int p = t / 9, k = t - p * 9;
        int wo = wo0 + p;
        float dy = off[(((size_t)b * 18 + 2 * k    ) * HH + ho) * WW + wo];
        float dx = off[(((size_t)b * 18 + 2 * k + 1) * HH + ho) * WW + wo];
        float m  = mask[(((size_t)b * 9 + k) * HH + ho) * WW + wo];
        float py = (float)(ho - 1 + k / 3) + dy;
        float px = (float)(wo - 1 + k % 3) + dx;
        float fy = floorf(py), fx = floorf(px);
        float ly = py - fy, lx = px - fx;
        int y0 = (int)fy, x0 = (int)fx;
        s_yx[t] = (y0 & 0xffff) | (x0 << 16);
        s_w[t * 4 + 0] = (1.f - ly) * (1.f - lx) * m;
        s_w[t * 4 + 1] = (1.f - ly) * lx * m;
        s_w[t * 4 + 2] = ly * (1.f - lx) * m;
        s_w[t * 4 + 3] = ly * lx * m;
    }
    __syncthreads();

    // phase 2: bilinear gather -> bf16 val[p][ck], ck = c*9+k
    const float* xb = x + (size_t)b * CIN * HW;
    for (int idx = tid; idx < MPB * CK; idx += 256) {
        int p  = idx / CK;
        int ck = idx - p * CK;
        int c  = ck / 9;
        int k  = ck - c * 9;
        int sk = p * 9 + k;
        int pv = s_yx[sk];
        int y0 = (int)(short)(pv & 0xffff);
        int x0 = pv >> 16;
        const float* xc = xb + c * HW;
        float v = 0.f;
        bool yok0 = (unsigned)y0 < (unsigned)HH;
        bool yok1 = (unsigned)(y0 + 1) < (unsigned)HH;
        bool xok0 = (unsigned)x0 < (unsigned)WW;
        bool xok1 = (unsigned)(x0 + 1) < (unsigned)WW;
        if (yok0 && xok0) v += s_w[sk * 4 + 0] * xc[y0 * WW + x0];
        if (yok0 && xok1) v += s_w[sk * 4 + 1] * xc[y0 * WW + x0 + 1];
        if (yok1 && xok0) v += s_w[sk * 4 + 2] * xc[(y0 + 1) * WW + x0];
        if (yok1 && xok1) v += s_w[sk * 4 + 3] * xc[(y0 + 1) * WW + x0 + 1];
        val[p * CKP + ck] = f2bf(v);
    }
    __syncthreads();

    // phase 3: MFMA GEMM. wave wv -> cols [wv*32, wv*32+32), rows 0..31.
    const int wv   = tid >> 6;
    const int lane = tid & 63;
    const int l15  = lane & 15;
    const int lk   = lane >> 4;            // 0..3
    const int co_s = tid >> 1;             // staging: row co
    const int half = tid & 1;              // staging: which 16-short half

    f32x4 acc[2][2];
#pragma unroll
    for (int m = 0; m < 2; ++m)
#pragma unroll
        for (int n = 0; n < 2; ++n) acc[m][n] = (f32x4)(0.f);

    for (int kc = 0; kc < 18; ++kc) {
        // stage wtb[:, kc*32 .. kc*32+32) -> wt[co][0..32)
        {
            const short8* src = (const short8*)(wtb + co_s * CK + kc * 32 + half * 16);
            short8* dst = (short8*)&wt[co_s * 40 + half * 16];
            dst[0] = src[0];
            dst[1] = src[1];
        }
        __syncthreads();
        short8 a0 = *(const short8*)&val[(l15     ) * CKP + kc * 32 + lk * 8];
        short8 a1 = *(const short8*)&val[(l15 + 16) * CKP + kc * 32 + lk * 8];
        short8 b0 = *(const short8*)&wt[(wv * 32 + l15     ) * 40 + lk * 8];
        short8 b1 = *(const short8*)&wt[(wv * 32 + l15 + 16) * 40 + lk * 8];
        acc[0][0] = __builtin_amdgcn_mfma_f32_16x16x32_bf16(a0, b0, acc[0][0], 0, 0, 0);
        acc[0][1] = __builtin_amdgcn_mfma_f32_16x16x32_bf16(a0, b1, acc[0][1], 0, 0, 0);
        acc[1][0] = __builtin_amdgcn_mfma_f32_16x16x32_bf16(a1, b0, acc[1][0], 0, 0, 0);
        acc[1][1] = __builtin_amdgcn_mfma_f32_16x16x32_bf16(a1, b1, acc[1][1], 0, 0, 0);
        __syncthreads();
    }

    // epilogue: C/D layout col=lane&15, row=(lane>>4)*4+reg  -> float4 stores
#pragma unroll
    for (int m = 0; m < 2; ++m) {
#pragma unroll
        for (int n = 0; n < 2; ++n) {
            int co = wv * 32 + n * 16 + l15;
            int p  = m * 16 + lk * 4;
            float bias = bd[co];
            float4 o;
            o.x = acc[m][n][0] + bias;
            o.y = acc[m][n][1] + bias;
            o.z = acc[m][n][2] + bias;
            o.w = acc[m][n][3] + bias;
            *(float4*)&y[((size_t)(b * COUT + co)) * HW + ho * WW + wo0 + p] = o;
        }
    }
}

// ---------------------------------------------------------------------------
// Kernel 3: per-channel BN stats -> scale/shift  [unchanged]
__global__ __launch_bounds__(256) void k_stats(const float* __restrict__ y,
                                               const float* __restrict__ gamma,
                                               const float* __restrict__ beta,
                                               float* __restrict__ sAB) {
    const int c = blockIdx.x;
    float s = 0.f, q = 0.f;
    for (int i4 = threadIdx.x; i4 < BB * HW / 4; i4 += 256) {
        int b = i4 >> 10;
        int pix4 = i4 & 1023;
        float4 v = ((const float4*)&y[((size_t)b * COUT + c) * HW])[pix4];
        s += v.x + v.y + v.z + v.w;
        q += v.x * v.x + v.y * v.y + v.z * v.z + v.w * v.w;
    }
#pragma unroll
    for (int o = 32; o > 0; o >>= 1) {
        s += __shfl_down(s, o);
        q += __shfl_down(q, o);
    }
    __shared__ float ss[4], sq[4];
    int wid = threadIdx.x >> 6;
    if ((threadIdx.x & 63) == 0) { ss[wid] = s; sq[wid] = q; }
    __syncthreads();
    if (threadIdx.x == 0) {
        s = ss[0] + ss[1] + ss[2] + ss[3];
        q = sq[0] + sq[1] + sq[2] + sq[3];
        const float invN = 1.f / (float)(BB * HW);
        float mean = s * invN;
        float var  = q * invN - mean * mean;
        float rinv = rsqrtf(var + 1e-5f);
        float A = gamma[c] * rinv;
        sAB[c]       = A;
        sAB[128 + c] = beta[c] - mean * A;
    }
}

// ---------------------------------------------------------------------------
// Kernel 4: normalize + exact GELU, vectorized  [unchanged]
__global__ __launch_bounds__(256) void k_norm_gelu(const float* __restrict__ y,
                                                   const float* __restrict__ sAB,
                                                   float* __restrict__ out) {
    int i4 = blockIdx.x * 256 + threadIdx.x;
    if (i4 >= (BB * COUT * HW) / 4) return;
    int c = (i4 >> 10) & 127;
    float A  = sAB[c];
    float Bc = sAB[128 + c];
    float4 v = ((const float4*)y)[i4];
    float4 r;
    float t;
    t = v.x * A + Bc; r.x = 0.5f * t * (1.f + erff(t * 0.70710678118654752f));
    t = v.y * A + Bc; r.y = 0.5f * t * (1.f + erff(t * 0.70710678118654752f));
    t = v.z * A + Bc; r.z = 0.5f * t * (1.f + erff(t * 0.70710678118654752f));
    t = v.w * A + Bc; r.w = 0.5f * t * (1.f + erff(t * 0.70710678118654752f));
    ((float4*)out)[i4] = r;
}

// ---------------------------------------------------------------------------
extern "C" void kernel_launch(void* const* d_in, const int* in_sizes, int n_in,
                              void* d_out, int out_size, void* d_ws, size_t ws_size,
                              hipStream_t stream) {
    const float* x     = (const float*)d_in[0];
    const float* w_p   = (const float*)d_in[1];
    const float* b_p   = (const float*)d_in[2];
    const float* w_m   = (const float*)d_in[3];
    const float* b_m   = (const float*)d_in[4];
    const float* w_d   = (const float*)d_in[5];
    const float* b_d   = (const float*)d_in[6];
    const float* gamma = (const float*)d_in[7];
    const float* beta  = (const float*)d_in[8];
    float* out = (float*)d_out;
    float* ws  = (float*)d_ws;

    float* off  = ws + OFF_OFF;
    float* mask = ws + MASK_OFF;
    float* y    = ws + Y_OFF;
    short* wtb  = (short*)(ws + WT_OFF);
    float* sAB  = ws + SAB_OFF;

    k_wd2bf<<<dim3((CK * COUT + 255) / 256), dim3(256), 0, stream>>>(w_d, wtb);
    k_conv_pm<<<dim3(BB * HW / 256), dim3(256), 0, stream>>>(x, w_p, b_p, w_m, b_m, off, mask);
    k_deform<<<dim3(BB * HW / MPB), dim3(256), 0, stream>>>(x, off, mask, wtb, b_d, y);
    k_stats<<<dim3(COUT), dim3(256), 0, stream>>>(y, gamma, beta, sAB);
    k_norm_gelu<<<dim3((BB * COUT * HW / 4 + 255) / 256), dim3(256), 0, stream>>>(y, sAB, out);
}

// Round 3
// 228.965 us; speedup vs baseline: 3.8643x; 1.9644x over previous
//
#include <hip/hip_runtime.h>
#include <math.h>

#define BB 16
#define CIN 64
#define HH 64
#define WW 64
#define COUT 128
#define HW 4096          // HH*WW
#define CK 576           // CIN*9
#define CKP 584          // padded LDS stride (shorts)

typedef __attribute__((ext_vector_type(8))) short short8;
typedef __attribute__((ext_vector_type(4))) short short4v;
typedef __attribute__((ext_vector_type(4))) float f32x4;

// ---- workspace layout (float indices) ----
#define OFF_OFF   0                         // B*18*HW  = 1179648 floats
#define MASK_OFF  1179648                   // B*9*HW   = 589824 floats
#define WT_OFF    1769472                   // CK*COUT shorts = 36864 floats
#define XH_OFF    1806336                   // B*HW*CIN shorts = 8388608 floats
#define SAB_OFF   10194944                  // 256 floats
// total ~40.8 MB. y lives in d_out.

__device__ __forceinline__ short f2bf(float f) {
    union { float f; unsigned u; } cv; cv.f = f;
    unsigned u = cv.u;
    unsigned r = (u + 0x7fffu + ((u >> 16) & 1u)) >> 16;
    return (short)r;
}
__device__ __forceinline__ float bf2f(short s) {
    union { unsigned u; float f; } cv;
    cv.u = ((unsigned)(unsigned short)s) << 16;
    return cv.f;
}

// ---------------------------------------------------------------------------
// Kernel A: transpose x NCHW -> NHWC bf16 (xh[b][y][x][c])
__global__ __launch_bounds__(256) void k_nhwc(const float* __restrict__ x,
                                              short* __restrict__ xh) {
    __shared__ float t[64][65];
    const int blk  = blockIdx.x;          // 1024 = 16 b * 64 pos-groups
    const int b    = blk >> 6;
    const int pos0 = (blk & 63) << 6;
    const int a    = threadIdx.x & 63;
    const int q    = threadIdx.x >> 6;    // 0..3
#pragma unroll
    for (int i = 0; i < 16; ++i) {
        int c = i * 4 + q;
        t[c][a] = x[((size_t)(b * CIN + c)) * HW + pos0 + a];   // coalesced
    }
    __syncthreads();
#pragma unroll
    for (int i = 0; i < 16; ++i) {
        int p = i * 4 + q;
        xh[((size_t)b * HW + pos0 + p) * CIN + a] = f2bf(t[a][p]); // coalesced, LDS conflict-free
    }
}

// ---------------------------------------------------------------------------
// Kernel B: repack w_d [co][c*9+k] f32 -> bf16 [co][k*64+c]
__global__ __launch_bounds__(256) void k_wd2bf(const float* __restrict__ wd,
                                               short* __restrict__ wtb) {
    int i = blockIdx.x * 256 + threadIdx.x;
    if (i >= CK * COUT) return;
    int co = i / CK;
    int kk = i - co * CK;
    int k  = kk >> 6;
    int c  = kk & 63;
    wtb[i] = f2bf(wd[co * CK + c * 9 + k]);
}

// ---------------------------------------------------------------------------
// Kernel 1: 3x3 conv producing offset (18 ch) and sigmoid(mask) (9 ch) [unchanged]
__global__ __launch_bounds__(256) void k_conv_pm(const float* __restrict__ x,
                                                 const float* __restrict__ wp,
                                                 const float* __restrict__ bp,
                                                 const float* __restrict__ wm,
                                                 const float* __restrict__ bm,
                                                 float* __restrict__ off,
                                                 float* __restrict__ mask) {
    int pos = blockIdx.x * 256 + threadIdx.x;
    int b  = pos >> 12;
    int ho = (pos >> 6) & 63;
    int wo = pos & 63;

    float acc[27];
#pragma unroll
    for (int t = 0; t < 27; ++t) acc[t] = 0.f;

    const float* xb = x + (size_t)b * CIN * HW;
    for (int c = 0; c < CIN; ++c) {
        float xv[9];
#pragma unroll
        for (int kh = 0; kh < 3; ++kh) {
            int iy = ho + kh - 1;
#pragma unroll
            for (int kw = 0; kw < 3; ++kw) {
                int ix = wo + kw - 1;
                bool v = (iy >= 0) && (iy < HH) && (ix >= 0) && (ix < WW);
                xv[kh * 3 + kw] = v ? xb[c * HW + iy * WW + ix] : 0.f;
            }
        }
#pragma unroll
        for (int t = 0; t < 18; ++t) {
#pragma unroll
            for (int k = 0; k < 9; ++k)
                acc[t] += xv[k] * wp[t * CK + c * 9 + k];
        }
#pragma unroll
        for (int t = 0; t < 9; ++t) {
#pragma unroll
            for (int k = 0; k < 9; ++k)
                acc[18 + t] += xv[k] * wm[t * CK + c * 9 + k];
        }
    }
#pragma unroll
    for (int t = 0; t < 18; ++t)
        off[((size_t)b * 18 + t) * HW + ho * WW + wo] = acc[t] + bp[t];
#pragma unroll
    for (int t = 0; t < 9; ++t) {
        float s = acc[18 + t] + bm[t];
        mask[((size_t)b * 9 + t) * HW + ho * WW + wo] = 1.f / (1.f + expf(-s));
    }
}

// ---------------------------------------------------------------------------
// Kernel 2: deformable conv, coalesced NHWC gather + barrier-free MFMA K-loop.
#define MPB 32
__global__ __launch_bounds__(256) void k_deform(const short* __restrict__ xh,
                                                const float* __restrict__ off,
                                                const float* __restrict__ mask,
                                                const short* __restrict__ wtb,
                                                const float* __restrict__ bd,
                                                float* __restrict__ y) {
    __shared__ short    val[MPB * CKP];     // 37376 B, bf16 A-tile [p][kk], kk=k*64+c
    __shared__ unsigned s_yx[MPB * 9];      // clamped coords packed as 4 bytes
    __shared__ float    s_w[MPB * 9 * 4];   // 4 corner weights (mask+validity folded)

    const int pos0 = blockIdx.x * MPB;
    const int b   = pos0 >> 12;
    const int ho  = (pos0 >> 6) & 63;
    const int wo0 = pos0 & 63;
    const int tid = threadIdx.x;

    // phase 1: sampling parameters (32 pos x 9 taps)
    for (int t = tid; t < MPB * 9; t += 256) {
        int p = t / 9, k = t - p * 9;
        int wo = wo0 + p;
        float dy = off[(((size_t)b * 18 + 2 * k    ) * HH + ho) * WW + wo];
        float dx = off[(((size_t)b * 18 + 2 * k + 1) * HH + ho) * WW + wo];
        float m  = mask[(((size_t)b * 9 + k) * HH + ho) * WW + wo];
        float py = (float)(ho - 1 + k / 3) + dy;
        float px = (float)(wo - 1 + k % 3) + dx;
        float fy = floorf(py), fx = floorf(px);
        float ly = py - fy, lx = px - fx;
        int y0 = (int)fy, x0 = (int)fx;
        int y1 = y0 + 1, x1 = x0 + 1;
        float vy0 = ((unsigned)y0 < 64u) ? 1.f : 0.f;
        float vy1 = ((unsigned)y1 < 64u) ? 1.f : 0.f;
        float vx0 = ((unsigned)x0 < 64u) ? 1.f : 0.f;
        float vx1 = ((unsigned)x1 < 64u) ? 1.f : 0.f;
        int y0c = min(max(y0, 0), 63), y1c = min(max(y1, 0), 63);
        int x0c = min(max(x0, 0), 63), x1c = min(max(x1, 0), 63);
        s_yx[t] = (unsigned)y0c | ((unsigned)y1c << 8) | ((unsigned)x0c << 16) | ((unsigned)x1c << 24);
        s_w[t * 4 + 0] = (1.f - ly) * (1.f - lx) * m * vy0 * vx0;
        s_w[t * 4 + 1] = (1.f - ly) * lx * m * vy0 * vx1;
        s_w[t * 4 + 2] = ly * (1.f - lx) * m * vy1 * vx0;
        s_w[t * 4 + 3] = ly * lx * m * vy1 * vx1;
    }
    __syncthreads();

    // phase 2: gather. 16 lanes per (p,k) tap; lane li -> channels li*4..li*4+3.
    {
        const int g  = tid >> 4;            // 16 tap-groups in flight
        const int li = tid & 15;
        const int c0 = li * 4;
        const short* xb = xh + (size_t)b * HW * CIN;
#pragma unroll 3
        for (int it = 0; it < 18; ++it) {
            int pr = it * 16 + g;           // 0..287
            int p = pr / 9, k = pr - p * 9;
            unsigned yx = s_yx[pr];
            int y0 = yx & 255, y1 = (yx >> 8) & 255;
            int x0 = (yx >> 16) & 255, x1 = yx >> 24;
            float w0 = s_w[pr * 4 + 0], w1 = s_w[pr * 4 + 1];
            float w2 = s_w[pr * 4 + 2], w3 = s_w[pr * 4 + 3];
            short4v v00 = *(const short4v*)&xb[(((y0 << 6) + x0) << 6) + c0];
            short4v v01 = *(const short4v*)&xb[(((y0 << 6) + x1) << 6) + c0];
            short4v v10 = *(const short4v*)&xb[(((y1 << 6) + x0) << 6) + c0];
            short4v v11 = *(const short4v*)&xb[(((y1 << 6) + x1) << 6) + c0];
            short4v o;
#pragma unroll
            for (int j = 0; j < 4; ++j) {
                float f = w0 * bf2f(v00[j]) + w1 * bf2f(v01[j])
                        + w2 * bf2f(v10[j]) + w3 * bf2f(v11[j]);
                o[j] = f2bf(f);
            }
            *(short4v*)&val[p * CKP + (k << 6) + c0] = o;   // contiguous ds_write_b64
        }
    }
    __syncthreads();

    // phase 3: MFMA GEMM, NO barriers. B-fragments straight from L2-hot wtb.
    const int wv   = tid >> 6;
    const int lane = tid & 63;
    const int l15  = lane & 15;
    const int lk   = lane >> 4;

    f32x4 acc[2][2];
#pragma unroll
    for (int m = 0; m < 2; ++m)
#pragma unroll
        for (int n = 0; n < 2; ++n) acc[m][n] = (f32x4)(0.f);

    const short* wrow0 = wtb + (size_t)(wv * 32 + l15) * CK + lk * 8;
    const short* wrow1 = wrow0 + 16 * CK;
#pragma unroll
    for (int kc = 0; kc < 18; ++kc) {
        short8 a0 = *(const short8*)&val[(l15     ) * CKP + kc * 32 + lk * 8];
        short8 a1 = *(const short8*)&val[(l15 + 16) * CKP + kc * 32 + lk * 8];
        short8 b0 = *(const short8*)&wrow0[kc * 32];
        short8 b1 = *(const short8*)&wrow1[kc * 32];
        acc[0][0] = __builtin_amdgcn_mfma_f32_16x16x32_bf16(a0, b0, acc[0][0], 0, 0, 0);
        acc[0][1] = __builtin_amdgcn_mfma_f32_16x16x32_bf16(a0, b1, acc[0][1], 0, 0, 0);
        acc[1][0] = __builtin_amdgcn_mfma_f32_16x16x32_bf16(a1, b0, acc[1][0], 0, 0, 0);
        acc[1][1] = __builtin_amdgcn_mfma_f32_16x16x32_bf16(a1, b1, acc[1][1], 0, 0, 0);
    }

    // epilogue: C/D layout col=lane&15 (co), row=(lane>>4)*4+reg (position)
#pragma unroll
    for (int m = 0; m < 2; ++m) {
#pragma unroll
        for (int n = 0; n < 2; ++n) {
            int co = wv * 32 + n * 16 + l15;
            int p  = m * 16 + lk * 4;
            float bias = bd[co];
            float4 o;
            o.x = acc[m][n][0] + bias;
            o.y = acc[m][n][1] + bias;
            o.z = acc[m][n][2] + bias;
            o.w = acc[m][n][3] + bias;
            *(float4*)&y[((size_t)(b * COUT + co)) * HW + ho * WW + wo0 + p] = o;
        }
    }
}

// ---------------------------------------------------------------------------
// Kernel 3: per-channel BN stats -> scale/shift
__global__ __launch_bounds__(256) void k_stats(const float* __restrict__ y,
                                               const float* __restrict__ gamma,
                                               const float* __restrict__ beta,
                                               float* __restrict__ sAB) {
    const int c = blockIdx.x;
    float s = 0.f, q = 0.f;
    for (int i4 = threadIdx.x; i4 < BB * HW / 4; i4 += 256) {
        int b = i4 >> 10;
        int pix4 = i4 & 1023;
        float4 v = ((const float4*)&y[((size_t)b * COUT + c) * HW])[pix4];
        s += v.x + v.y + v.z + v.w;
        q += v.x * v.x + v.y * v.y + v.z * v.z + v.w * v.w;
    }
#pragma unroll
    for (int o = 32; o > 0; o >>= 1) {
        s += __shfl_down(s, o);
        q += __shfl_down(q, o);
    }
    __shared__ float ss[4], sq[4];
    int wid = threadIdx.x >> 6;
    if ((threadIdx.x & 63) == 0) { ss[wid] = s; sq[wid] = q; }
    __syncthreads();
    if (threadIdx.x == 0) {
        s = ss[0] + ss[1] + ss[2] + ss[3];
        q = sq[0] + sq[1] + sq[2] + sq[3];
        const float invN = 1.f / (float)(BB * HW);
        float mean = s * invN;
        float var  = q * invN - mean * mean;
        float rinv = rsqrtf(var + 1e-5f);
        float A = gamma[c] * rinv;
        sAB[c]       = A;
        sAB[128 + c] = beta[c] - mean * A;
    }
}

// ---------------------------------------------------------------------------
// Kernel 4: normalize + exact GELU (in-place on d_out)
__global__ __launch_bounds__(256) void k_norm_gelu(float* __restrict__ y,
                                                   const float* __restrict__ sAB) {
    int i4 = blockIdx.x * 256 + threadIdx.x;
    if (i4 >= (BB * COUT * HW) / 4) return;
    int c = (i4 >> 10) & 127;
    float A  = sAB[c];
    float Bc = sAB[128 + c];
    float4 v = ((const float4*)y)[i4];
    float4 r;
    float t;
    t = v.x * A + Bc; r.x = 0.5f * t * (1.f + erff(t * 0.70710678118654752f));
    t = v.y * A + Bc; r.y = 0.5f * t * (1.f + erff(t * 0.70710678118654752f));
    t = v.z * A + Bc; r.z = 0.5f * t * (1.f + erff(t * 0.70710678118654752f));
    t = v.w * A + Bc; r.w = 0.5f * t * (1.f + erff(t * 0.70710678118654752f));
    ((float4*)y)[i4] = r;
}

// ---------------------------------------------------------------------------
extern "C" void kernel_launch(void* const* d_in, const int* in_sizes, int n_in,
                              void* d_out, int out_size, void* d_ws, size_t ws_size,
                              hipStream_t stream) {
    const float* x     = (const float*)d_in[0];
    const float* w_p   = (const float*)d_in[1];
    const float* b_p   = (const float*)d_in[2];
    const float* w_m   = (const float*)d_in[3];
    const float* b_m   = (const float*)d_in[4];
    const float* w_d   = (const float*)d_in[5];
    const float* b_d   = (const float*)d_in[6];
    const float* gamma = (const float*)d_in[7];
    const float* beta  = (const float*)d_in[8];
    float* ws  = (float*)d_ws;
    float* y   = (float*)d_out;             // deform output lives in d_out

    float* off  = ws + OFF_OFF;
    float* mask = ws + MASK_OFF;
    short* wtb  = (short*)(ws + WT_OFF);
    short* xh   = (short*)(ws + XH_OFF);
    float* sAB  = ws + SAB_OFF;

    k_nhwc<<<dim3(1024), dim3(256), 0, stream>>>(x, xh);
    k_wd2bf<<<dim3((CK * COUT + 255) / 256), dim3(256), 0, stream>>>(w_d, wtb);
    k_conv_pm<<<dim3(BB * HW / 256), dim3(256), 0, stream>>>(x, w_p, b_p, w_m, b_m, off, mask);
    k_deform<<<dim3(BB * HW / MPB), dim3(256), 0, stream>>>(xh, off, mask, wtb, b_d, y);
    k_stats<<<dim3(COUT), dim3(256), 0, stream>>>(y, gamma, beta, sAB);
    k_norm_gelu<<<dim3((BB * COUT * HW / 4 + 255) / 256), dim3(256), 0, stream>>>(y, sAB);
}

// Round 4
// 137.052 us; speedup vs baseline: 6.4558x; 1.6706x over previous
//
#include <hip/hip_runtime.h>
#include <math.h>

#define BB 16
#define CIN 64
#define HH 64
#define WW 64
#define COUT 128
#define HW 4096          // HH*WW
#define CK 576           // CIN*9
#define CKP 584          // padded LDS stride (shorts)

typedef __attribute__((ext_vector_type(8))) short short8;
typedef __attribute__((ext_vector_type(4))) short short4v;
typedef __attribute__((ext_vector_type(4))) float f32x4;

// ---- workspace layout (float indices) ----
#define OFF_OFF   0                         // B*18*HW  = 1179648 floats
#define MASK_OFF  1179648                   // B*9*HW   = 589824 floats
#define WT_OFF    1769472                   // CK*COUT shorts = 36864 floats
#define WPM_OFF   1806336                   // 32*CK shorts = 9216 floats
#define XH_OFF    1815552                   // B*HW*CIN shorts = 8388608 floats
#define SAB_OFF   10204160                  // 256 floats
// total ~40.8 MB. y lives in d_out.

__device__ __forceinline__ short f2bf(float f) {
    union { float f; unsigned u; } cv; cv.f = f;
    unsigned u = cv.u;
    unsigned r = (u + 0x7fffu + ((u >> 16) & 1u)) >> 16;
    return (short)r;
}
__device__ __forceinline__ float bf2f(short s) {
    union { unsigned u; float f; } cv;
    cv.u = ((unsigned)(unsigned short)s) << 16;
    return cv.f;
}

// ---------------------------------------------------------------------------
// Kernel A: transpose x NCHW -> NHWC bf16 (xh[b][y][x][c])
__global__ __launch_bounds__(256) void k_nhwc(const float* __restrict__ x,
                                              short* __restrict__ xh) {
    __shared__ float t[64][65];
    const int blk  = blockIdx.x;          // 1024 = 16 b * 64 pos-groups
    const int b    = blk >> 6;
    const int pos0 = (blk & 63) << 6;
    const int a    = threadIdx.x & 63;
    const int q    = threadIdx.x >> 6;    // 0..3
#pragma unroll
    for (int i = 0; i < 16; ++i) {
        int c = i * 4 + q;
        t[c][a] = x[((size_t)(b * CIN + c)) * HW + pos0 + a];   // coalesced
    }
    __syncthreads();
#pragma unroll
    for (int i = 0; i < 16; ++i) {
        int p = i * 4 + q;
        xh[((size_t)b * HW + pos0 + p) * CIN + a] = f2bf(t[a][p]); // coalesced
    }
}

// ---------------------------------------------------------------------------
// Kernel B: pack weights to bf16, K-order kk = k*64+c.
//  wtb[co][kk]  co<128   from w_d
//  wpm[t][kk]   t<18: w_p, 18<=t<27: w_m, t>=27: zero
__global__ __launch_bounds__(256) void k_pack(const float* __restrict__ wd,
                                              const float* __restrict__ wp,
                                              const float* __restrict__ wm,
                                              short* __restrict__ wtb,
                                              short* __restrict__ wpm) {
    int i = blockIdx.x * 256 + threadIdx.x;
    if (i < CK * COUT) {
        int co = i / CK;
        int kk = i - co * CK;
        int k  = kk >> 6;
        int c  = kk & 63;
        wtb[i] = f2bf(wd[co * CK + c * 9 + k]);
        return;
    }
    i -= CK * COUT;
    if (i < 32 * CK) {
        int t  = i / CK;
        int kk = i - t * CK;
        int k  = kk >> 6;
        int c  = kk & 63;
        float v = 0.f;
        if (t < 18)      v = wp[t * CK + c * 9 + k];
        else if (t < 27) v = wm[(t - 18) * CK + c * 9 + k];
        wpm[i] = f2bf(v);
    }
}

// ---------------------------------------------------------------------------
// Kernel 1: offset/mask conv as barrier-free implicit MFMA GEMM.
// Block = 32 positions, 4 waves = 2x2 grid of 16x16 output tiles.
// A-fragments straight from NHWC xh (16B contiguous); B from L2-hot wpm.
__global__ __launch_bounds__(256) void k_conv_pm(const short* __restrict__ xh,
                                                 const short* __restrict__ wpm,
                                                 const float* __restrict__ bp,
                                                 const float* __restrict__ bm,
                                                 float* __restrict__ off,
                                                 float* __restrict__ mask) {
    const int pos0 = blockIdx.x * 32;
    const int b   = pos0 >> 12;
    const int ho  = (pos0 >> 6) & 63;
    const int wo0 = pos0 & 63;

    const int tid  = threadIdx.x;
    const int wv   = tid >> 6;
    const int lane = tid & 63;
    const int l15  = lane & 15;
    const int lk   = lane >> 4;            // 0..3
    const int mw   = wv & 1;               // position half
    const int nw   = wv >> 1;              // outch half

    const int p    = mw * 16 + l15;        // A row: position in tile
    const int wo   = wo0 + p;
    const int t    = nw * 16 + l15;        // B row: out channel

    const short* xb  = xh + (size_t)b * HW * CIN;
    const short* wr  = wpm + t * CK;

    f32x4 acc = (f32x4)(0.f);
#pragma unroll
    for (int kc = 0; kc < 18; ++kc) {
        const int k  = kc >> 1;            // tap 0..8
        const int c0 = (kc & 1) * 32 + lk * 8;
        const int yy = ho - 1 + k / 3;
        const int xx = wo - 1 + k % 3;
        const bool valid = ((unsigned)yy < 64u) & ((unsigned)xx < 64u);
        const int yyc = min(max(yy, 0), 63);
        const int xxc = min(max(xx, 0), 63);
        short8 a = *(const short8*)&xb[(((yyc << 6) + xxc) << 6) + c0];
        if (!valid) a = (short8)0;
        short8 bfr = *(const short8*)&wr[kc * 32 + lk * 8];
        acc = __builtin_amdgcn_mfma_f32_16x16x32_bf16(a, bfr, acc, 0, 0, 0);
    }

    // C/D: col=lane&15 -> out channel t, row=(lane>>4)*4+reg -> position
    const int pst = wo0 + mw * 16 + lk * 4;
    if (t < 18) {
        float bias = bp[t];
        float4 o;
        o.x = acc[0] + bias; o.y = acc[1] + bias;
        o.z = acc[2] + bias; o.w = acc[3] + bias;
        *(float4*)&off[(((size_t)b * 18 + t) * HH + ho) * WW + pst] = o;
    } else if (t < 27) {
        float bias = bm[t - 18];
        float4 o;
        o.x = 1.f / (1.f + expf(-(acc[0] + bias)));
        o.y = 1.f / (1.f + expf(-(acc[1] + bias)));
        o.z = 1.f / (1.f + expf(-(acc[2] + bias)));
        o.w = 1.f / (1.f + expf(-(acc[3] + bias)));
        *(float4*)&mask[(((size_t)b * 9 + (t - 18)) * HH + ho) * WW + pst] = o;
    }
}

// ---------------------------------------------------------------------------
// Kernel 2: deformable conv, coalesced NHWC gather + barrier-free MFMA K-loop.
#define MPB 32
__global__ __launch_bounds__(256) void k_deform(const short* __restrict__ xh,
                                                const float* __restrict__ off,
                                                const float* __restrict__ mask,
                                                const short* __restrict__ wtb,
                                                const float* __restrict__ bd,
                                                float* __restrict__ y) {
    __shared__ short    val[MPB * CKP];     // 37376 B, bf16 A-tile [p][kk], kk=k*64+c
    __shared__ unsigned s_yx[MPB * 9];      // clamped coords packed as 4 bytes
    __shared__ float    s_w[MPB * 9 * 4];   // 4 corner weights (mask+validity folded)

    const int pos0 = blockIdx.x * MPB;
    const int b   = pos0 >> 12;
    const int ho  = (pos0 >> 6) & 63;
    const int wo0 = pos0 & 63;
    const int tid = threadIdx.x;

    // phase 1: sampling parameters (32 pos x 9 taps)
    for (int t = tid; t < MPB * 9; t += 256) {
        int p = t / 9, k = t - p * 9;
        int wo = wo0 + p;
        float dy = off[(((size_t)b * 18 + 2 * k    ) * HH + ho) * WW + wo];
        float dx = off[(((size_t)b * 18 + 2 * k + 1) * HH + ho) * WW + wo];
        float m  = mask[(((size_t)b * 9 + k) * HH + ho) * WW + wo];
        float py = (float)(ho - 1 + k / 3) + dy;
        float px = (float)(wo - 1 + k % 3) + dx;
        float fy = floorf(py), fx = floorf(px);
        float ly = py - fy, lx = px - fx;
        int y0 = (int)fy, x0 = (int)fx;
        int y1 = y0 + 1, x1 = x0 + 1;
        float vy0 = ((unsigned)y0 < 64u) ? 1.f : 0.f;
        float vy1 = ((unsigned)y1 < 64u) ? 1.f : 0.f;
        float vx0 = ((unsigned)x0 < 64u) ? 1.f : 0.f;
        float vx1 = ((unsigned)x1 < 64u) ? 1.f : 0.f;
        int y0c = min(max(y0, 0), 63), y1c = min(max(y1, 0), 63);
        int x0c = min(max(x0, 0), 63), x1c = min(max(x1, 0), 63);
        s_yx[t] = (unsigned)y0c | ((unsigned)y1c << 8) | ((unsigned)x0c << 16) | ((unsigned)x1c << 24);
        s_w[t * 4 + 0] = (1.f - ly) * (1.f - lx) * m * vy0 * vx0;
        s_w[t * 4 + 1] = (1.f - ly) * lx * m * vy0 * vx1;
        s_w[t * 4 + 2] = ly * (1.f - lx) * m * vy1 * vx0;
        s_w[t * 4 + 3] = ly * lx * m * vy1 * vx1;
    }
    __syncthreads();

    // phase 2: gather. 16 lanes per (p,k) tap; lane li -> channels li*4..li*4+3.
    {
        const int g  = tid >> 4;
        const int li = tid & 15;
        const int c0 = li * 4;
        const short* xb = xh + (size_t)b * HW * CIN;
#pragma unroll 3
        for (int it = 0; it < 18; ++it) {
            int pr = it * 16 + g;
            int p = pr / 9, k = pr - p * 9;
            unsigned yx = s_yx[pr];
            int y0 = yx & 255, y1 = (yx >> 8) & 255;
            int x0 = (yx >> 16) & 255, x1 = yx >> 24;
            float w0 = s_w[pr * 4 + 0], w1 = s_w[pr * 4 + 1];
            float w2 = s_w[pr * 4 + 2], w3 = s_w[pr * 4 + 3];
            short4v v00 = *(const short4v*)&xb[(((y0 << 6) + x0) << 6) + c0];
            short4v v01 = *(const short4v*)&xb[(((y0 << 6) + x1) << 6) + c0];
            short4v v10 = *(const short4v*)&xb[(((y1 << 6) + x0) << 6) + c0];
            short4v v11 = *(const short4v*)&xb[(((y1 << 6) + x1) << 6) + c0];
            short4v o;
#pragma unroll
            for (int j = 0; j < 4; ++j) {
                float f = w0 * bf2f(v00[j]) + w1 * bf2f(v01[j])
                        + w2 * bf2f(v10[j]) + w3 * bf2f(v11[j]);
                o[j] = f2bf(f);
            }
            *(short4v*)&val[p * CKP + (k << 6) + c0] = o;
        }
    }
    __syncthreads();

    // phase 3: MFMA GEMM, NO barriers. B-fragments straight from L2-hot wtb.
    const int wv   = tid >> 6;
    const int lane = tid & 63;
    const int l15  = lane & 15;
    const int lk   = lane >> 4;

    f32x4 acc[2][2];
#pragma unroll
    for (int m = 0; m < 2; ++m)
#pragma unroll
        for (int n = 0; n < 2; ++n) acc[m][n] = (f32x4)(0.f);

    const short* wrow0 = wtb + (size_t)(wv * 32 + l15) * CK + lk * 8;
    const short* wrow1 = wrow0 + 16 * CK;
#pragma unroll
    for (int kc = 0; kc < 18; ++kc) {
        short8 a0 = *(const short8*)&val[(l15     ) * CKP + kc * 32 + lk * 8];
        short8 a1 = *(const short8*)&val[(l15 + 16) * CKP + kc * 32 + lk * 8];
        short8 b0 = *(const short8*)&wrow0[kc * 32];
        short8 b1 = *(const short8*)&wrow1[kc * 32];
        acc[0][0] = __builtin_amdgcn_mfma_f32_16x16x32_bf16(a0, b0, acc[0][0], 0, 0, 0);
        acc[0][1] = __builtin_amdgcn_mfma_f32_16x16x32_bf16(a0, b1, acc[0][1], 0, 0, 0);
        acc[1][0] = __builtin_amdgcn_mfma_f32_16x16x32_bf16(a1, b0, acc[1][0], 0, 0, 0);
        acc[1][1] = __builtin_amdgcn_mfma_f32_16x16x32_bf16(a1, b1, acc[1][1], 0, 0, 0);
    }

#pragma unroll
    for (int m = 0; m < 2; ++m) {
#pragma unroll
        for (int n = 0; n < 2; ++n) {
            int co = wv * 32 + n * 16 + l15;
            int p  = m * 16 + lk * 4;
            float bias = bd[co];
            float4 o;
            o.x = acc[m][n][0] + bias;
            o.y = acc[m][n][1] + bias;
            o.z = acc[m][n][2] + bias;
            o.w = acc[m][n][3] + bias;
            *(float4*)&y[((size_t)(b * COUT + co)) * HW + ho * WW + wo0 + p] = o;
        }
    }
}

// ---------------------------------------------------------------------------
// Kernel 3: per-channel BN stats -> scale/shift
__global__ __launch_bounds__(256) void k_stats(const float* __restrict__ y,
                                               const float* __restrict__ gamma,
                                               const float* __restrict__ beta,
                                               float* __restrict__ sAB) {
    const int c = blockIdx.x;
    float s = 0.f, q = 0.f;
    for (int i4 = threadIdx.x; i4 < BB * HW / 4; i4 += 256) {
        int b = i4 >> 10;
        int pix4 = i4 & 1023;
        float4 v = ((const float4*)&y[((size_t)b * COUT + c) * HW])[pix4];
        s += v.x + v.y + v.z + v.w;
        q += v.x * v.x + v.y * v.y + v.z * v.z + v.w * v.w;
    }
#pragma unroll
    for (int o = 32; o > 0; o >>= 1) {
        s += __shfl_down(s, o);
        q += __shfl_down(q, o);
    }
    __shared__ float ss[4], sq[4];
    int wid = threadIdx.x >> 6;
    if ((threadIdx.x & 63) == 0) { ss[wid] = s; sq[wid] = q; }
    __syncthreads();
    if (threadIdx.x == 0) {
        s = ss[0] + ss[1] + ss[2] + ss[3];
        q = sq[0] + sq[1] + sq[2] + sq[3];
        const float invN = 1.f / (float)(BB * HW);
        float mean = s * invN;
        float var  = q * invN - mean * mean;
        float rinv = rsqrtf(var + 1e-5f);
        float A = gamma[c] * rinv;
        sAB[c]       = A;
        sAB[128 + c] = beta[c] - mean * A;
    }
}

// ---------------------------------------------------------------------------
// Kernel 4: normalize + exact GELU (in-place on d_out)
__global__ __launch_bounds__(256) void k_norm_gelu(float* __restrict__ y,
                                                   const float* __restrict__ sAB) {
    int i4 = blockIdx.x * 256 + threadIdx.x;
    if (i4 >= (BB * COUT * HW) / 4) return;
    int c = (i4 >> 10) & 127;
    float A  = sAB[c];
    float Bc = sAB[128 + c];
    float4 v = ((const float4*)y)[i4];
    float4 r;
    float t;
    t = v.x * A + Bc; r.x = 0.5f * t * (1.f + erff(t * 0.70710678118654752f));
    t = v.y * A + Bc; r.y = 0.5f * t * (1.f + erff(t * 0.70710678118654752f));
    t = v.z * A + Bc; r.z = 0.5f * t * (1.f + erff(t * 0.70710678118654752f));
    t = v.w * A + Bc; r.w = 0.5f * t * (1.f + erff(t * 0.70710678118654752f));
    ((float4*)y)[i4] = r;
}

// ---------------------------------------------------------------------------
extern "C" void kernel_launch(void* const* d_in, const int* in_sizes, int n_in,
                              void* d_out, int out_size, void* d_ws, size_t ws_size,
                              hipStream_t stream) {
    const float* x     = (const float*)d_in[0];
    const float* w_p   = (const float*)d_in[1];
    const float* b_p   = (const float*)d_in[2];
    const float* w_m   = (const float*)d_in[3];
    const float* b_m   = (const float*)d_in[4];
    const float* w_d   = (const float*)d_in[5];
    const float* b_d   = (const float*)d_in[6];
    const float* gamma = (const float*)d_in[7];
    const float* beta  = (const float*)d_in[8];
    float* ws  = (float*)d_ws;
    float* y   = (float*)d_out;             // deform output lives in d_out

    float* off  = ws + OFF_OFF;
    float* mask = ws + MASK_OFF;
    short* wtb  = (short*)(ws + WT_OFF);
    short* wpm  = (short*)(ws + WPM_OFF);
    short* xh   = (short*)(ws + XH_OFF);
    float* sAB  = ws + SAB_OFF;

    k_nhwc<<<dim3(1024), dim3(256), 0, stream>>>(x, xh);
    k_pack<<<dim3((CK * COUT + 32 * CK + 255) / 256), dim3(256), 0, stream>>>(w_d, w_p, w_m, wtb, wpm);
    k_conv_pm<<<dim3(BB * HW / 32), dim3(256), 0, stream>>>(xh, wpm, b_p, b_m, off, mask);
    k_deform<<<dim3(BB * HW / MPB), dim3(256), 0, stream>>>(xh, off, mask, wtb, b_d, y);
    k_stats<<<dim3(COUT), dim3(256), 0, stream>>>(y, gamma, beta, sAB);
    k_norm_gelu<<<dim3((BB * COUT * HW / 4 + 255) / 256), dim3(256), 0, stream>>>(y, sAB);
}